// Round 8
// baseline (47.697 us; speedup 1.0000x reference)
//
#include <hip/hip_runtime.h>
#include <math.h>

// Batched tridiagonal solve A(exp(alpha)) u = f_rhs via chunked partition
// (SPIKE-style), one wave per row.
// Round 8 = round 6 numerics + round 7's structural (non-numeric) wins:
//  - phase 1 (in-chunk) + phase 3 (recovery) in f32, rcp with 1 NR  [r6, pass]
//  - phase 2 boundary scan in f64  [r7's f32 scan FAILED: the global solve
//    carries kappa ~ n^2 ~ 2^20; the projective scan's cancellations need
//    f64. Sequential f32 Thomas survives (backward-stable), scans don't.]
//  - h2 folded into staged f (linear, ulp-equivalent)
//  - no ostage: per-lane 64B-sector direct stores (L2 write-combining);
//    LDS 21.5 -> 4.3 KB, one less __syncthreads
//  - launch_bounds(256,2): VGPR cap 256 so the ~90-value live set fits
//    without spills (r6's VGPR_Count=48 < live set => hidden spill cost)

constexpr int BT   = 16384;
constexpr int MPTS = 1024;
constexpr int NU   = 1023;   // real unknowns
constexpr int CS   = 16;     // chunk size (per lane)
constexpr int WPB  = 4;      // rows (waves) per block

__device__ __forceinline__ float frcp(float x) {
    float r = __builtin_amdgcn_rcpf(x);        // v_rcp_f32
    r = fmaf(r, fmaf(-x, r, 1.0f), r);         // 1 NR -> ~0.5 ulp
    return r;
}
__device__ __forceinline__ double drcp(double x) {
    double r = __builtin_amdgcn_rcp(x);        // v_rcp_f64, ~2^-27
    r = fma(r, fma(-x, r, 1.0), r);            // 1 NR -> ~2^-54
    return r;
}

__global__ __launch_bounds__(WPB * 64, 2)
void pt_kernel(const float* __restrict__ alpha,
               const float* __restrict__ f_rhs,
               float* __restrict__ out) {
    const int t    = threadIdx.x;
    const int lane = t & 63;
    const int row  = blockIdx.x * WPB + (t >> 6);
    const int s    = lane * CS;          // first global index of this chunk

    __shared__ float f_lds[1056];        // swizzled: h2*f[j] at j + (j>>5)

    const float h2 = (float)(1.0 / (1023.0 * 1023.0));
    for (int i = t; i < NU; i += WPB * 64) f_lds[i + (i >> 5)] = h2 * f_rhs[i];
    if (t == 0) f_lds[1023 + (1023 >> 5)] = 0.0f;  // identity-pad row: f = 0

    // ---------------- load K = exp(alpha) for this chunk (17 values) --------
    const float* arow = alpha + (size_t)row * MPTS;
    float kf[CS + 1];
    #pragma unroll
    for (int q = 0; q < 4; ++q) {
        const float4 v = *reinterpret_cast<const float4*>(arow + s + 4 * q);
        kf[4 * q + 0] = expf(v.x);
        kf[4 * q + 1] = expf(v.y);
        kf[4 * q + 2] = expf(v.z);
        kf[4 * q + 3] = expf(v.w);
    }
    {
        float kx = (lane < 63) ? arow[s + CS] : 0.0f;  // lane63: exp(0)=1
        kf[CS] = expf(kx);
    }
    // lane 63 pre-patch: kn at j=1022 -> 0 gives b=kc, d=0 there; at j=1023
    // kc=0, kn=1 gives the identity row (b=1) with f=0.
    if (lane == 63) kf[15] = 0.0f;

    __syncthreads();  // f_lds ready

    // ---------------- phase 1a: in-chunk forward elimination (f32) ----------
    float cA[CS], uA[CS], vA[CS];
    {
        // cp_init = 1 for lane 0 folds the j=0 boundary (den = 2*K0 + K1).
        float cp = (lane == 0) ? 1.0f : 0.0f;
        float up = 0.0f, vp = 1.0f;
        #pragma unroll
        for (int i = 0; i < CS; ++i) {
            const int j = s + i;
            const float kc = kf[i];
            const float kn = kf[i + 1];
            const float b  = kc + kn;
            const float f  = f_lds[j + (j >> 5)];
            const float den = fmaf(kc, cp, b);
            const float r   = frcp(den);
            float ci = -kn * r;
            const float ui = fmaf(kc, up, f) * r;
            const float vi = (kc * vp) * r;
            if (i == CS - 1) ci = (lane == 63) ? 0.0f : ci;  // identity pad row
            cA[i] = ci; uA[i] = ui; vA[i] = vi;
            cp = ci; up = ui; vp = vi;
        }
    }

    // ---------------- phase 1b: in-chunk back substitution (f32) ------------
    // u_i = D_i + A_i * uL + B_i * uR   (stored in place: uA=D, vA=A, cA=B)
    float De_f, Ae_f, Be_f, Ds_f, As_f, Bs_f;
    {
        float Dn = uA[CS - 1], An = vA[CS - 1], Bn = -cA[CS - 1];
        De_f = Dn; Ae_f = An; Be_f = Bn;
        uA[CS - 1] = Dn; vA[CS - 1] = An; cA[CS - 1] = Bn;
        #pragma unroll
        for (int i = CS - 2; i >= 0; --i) {
            const float ci = cA[i];
            Dn = fmaf(-ci, Dn, uA[i]);
            An = fmaf(-ci, An, vA[i]);
            Bn = -ci * Bn;
            uA[i] = Dn; vA[i] = An; cA[i] = Bn;
        }
        Ds_f = uA[0]; As_f = vA[0]; Bs_f = cA[0];
    }

    // ---------------- phase 2: reduced boundary system (f64) ----------------
    // y_p = Ds + As*x_{p-1} + Bs*y_{p+1};  x_p = De + Ae*x_{p-1} + Be*y_{p+1}
    // Projective 3x3 suffix scan, kept normalized so m22 == 1 (6 entries).
    const double Ds = (double)Ds_f, As = (double)As_f, Bs = (double)Bs_f;
    const double De = (double)De_f, Ae = (double)Ae_f, Be = (double)Be_f;
    double m00 = Bs;
    double m01 = fma(Bs, De, -(Ds * Be));
    double m02 = Ds;
    double m11 = fma(Bs, Ae, -(As * Be));
    double m12 = As;
    double m21 = -Be;

    #pragma unroll
    for (int dlt = 1; dlt < 64; dlt <<= 1) {
        const bool val = (lane + dlt) < 64;
        double b00 = __shfl_down(m00, dlt); b00 = val ? b00 : 1.0;
        double b01 = __shfl_down(m01, dlt); b01 = val ? b01 : 0.0;
        double b02 = __shfl_down(m02, dlt); b02 = val ? b02 : 0.0;
        double b11 = __shfl_down(m11, dlt); b11 = val ? b11 : 1.0;
        double b12 = __shfl_down(m12, dlt); b12 = val ? b12 : 0.0;
        double b21 = __shfl_down(m21, dlt); b21 = val ? b21 : 0.0;
        const double n00 = m00 * b00;
        const double n01 = fma(m00, b01, fma(m01, b11, m02 * b21));
        const double n02 = fma(m00, b02, fma(m01, b12, m02));   // b22 == 1
        const double n11 = fma(m11, b11, m12 * b21);
        const double n12 = fma(m11, b12, m12);
        const double n21 = fma(m21, b11, b21);                  // m22 == 1
        const double n22 = fma(m21, b12, 1.0);
        const double rn = drcp(n22);       // n22 in (0,1]: strict dominance
        m00 = n00 * rn; m01 = n01 * rn; m02 = n02 * rn;
        m11 = n11 * rn; m12 = n12 * rn; m21 = n21 * rn;
    }
    // y_p = alf + bet * x_{p-1}   (m22 == 1)
    const double alf = m02;
    const double bet = m12;
    double alfn = __shfl_down(alf, 1); alfn = (lane == 63) ? 0.0 : alfn;
    double betn = __shfl_down(bet, 1); betn = (lane == 63) ? 0.0 : betn;

    // x_p = dl + gm * x_{p-1}
    const double tt = drcp(fma(-Be, betn, 1.0));
    const double dl = fma(Be, alfn, De) * tt;
    const double gm = Ae * tt;

    // Affine prefix scan for x (x_{-1} = 0).
    double X = dl, G = gm;
    #pragma unroll
    for (int dlt = 1; dlt < 64; dlt <<= 1) {
        double bx = __shfl_up(X, dlt);
        double bg = __shfl_up(G, dlt);
        const bool val = lane >= dlt;
        bx = val ? bx : 0.0;
        bg = val ? bg : 1.0;
        X = fma(G, bx, X);
        G = G * bg;
    }
    double xp = __shfl_up(X, 1);
    const double uLd = (lane == 0) ? 0.0 : xp;          // u_{s-1}
    const double Y   = fma(bet, uLd, alf);              // y_p = u_s
    double yn = __shfl_down(Y, 1);
    const double uRd = (lane == 63) ? 0.0 : yn;         // u_{e+1}

    // ---------------- phase 3: recover interior + direct stores (f32) -------
    // Lane L's 16 dword stores cover exactly bytes [64L, 64L+64) of the row:
    // temporally adjacent partial-line writes -> L2 write-combining.
    const float uL = (float)uLd;
    const float uR = (float)uRd;
    float* orow = out + (size_t)row * NU;
    #pragma unroll
    for (int i = 0; i < CS - 1; ++i) {
        const float uu = fmaf(vA[i], uL, fmaf(cA[i], uR, uA[i]));
        orow[s + i] = uu;                  // s+i <= 1022 always
    }
    {
        const float uu = fmaf(vA[CS - 1], uL, fmaf(cA[CS - 1], uR, uA[CS - 1]));
        if (lane < 63) orow[s + CS - 1] = uu;   // j = 1023 is the pad row
    }
}

extern "C" void kernel_launch(void* const* d_in, const int* in_sizes, int n_in,
                              void* d_out, int out_size, void* d_ws, size_t ws_size,
                              hipStream_t stream) {
    const float* alpha = (const float*)d_in[0];
    const float* f_rhs = (const float*)d_in[1];
    float* out = (float*)d_out;

    dim3 grid(BT / WPB), block(WPB * 64);
    pt_kernel<<<grid, block, 0, stream>>>(alpha, f_rhs, out);
}

// Round 9
// 39.732 us; speedup vs baseline: 1.2005x; 1.2005x over previous
//
#include <hip/hip_runtime.h>
#include <math.h>

// Batched tridiagonal solve A(exp(alpha)) u = f_rhs via chunked partition
// (SPIKE-style), one wave per row.
// Round 9: NO ARRAY crosses phase 2 (kills the r3-r8 register spills).
//  - phase 1: two interleaved 3-scalar chains (fwd -> (De,Ae,Be) free at the
//    last step; reverse elimination -> (Ds,As,Bs) at its last step). Zero
//    arrays stored.
//  - phase 2: f64 projective scan, verbatim from passing r8 (f32 FAILED r7).
//  - phase 3: re-solve the chunk with uL/uR folded into f (linearity),
//    storing only c3[16]+u3[16]; back-sub; ostage LDS coalesced writes
//    (r8's direct sector stores cost +9us: 64-line address divergence/inst).
//  - peak live ~60 VGPR -> fits compiler's occupancy-driven budget, no spill.

constexpr int BT   = 16384;
constexpr int MPTS = 1024;
constexpr int NU   = 1023;   // real unknowns
constexpr int CS   = 16;     // chunk size (per lane)
constexpr int WPB  = 4;      // rows (waves) per block

__device__ __forceinline__ float frcp(float x) {
    float r = __builtin_amdgcn_rcpf(x);        // v_rcp_f32
    r = fmaf(r, fmaf(-x, r, 1.0f), r);         // 1 NR -> ~0.5 ulp
    return r;
}
__device__ __forceinline__ double drcp(double x) {
    double r = __builtin_amdgcn_rcp(x);        // v_rcp_f64, ~2^-27
    r = fma(r, fma(-x, r, 1.0), r);            // 1 NR -> ~2^-54
    return r;
}
__device__ __forceinline__ int sw(int j) { return j + (j >> 5); }

__global__ __launch_bounds__(WPB * 64, 4)
void pt_kernel(const float* __restrict__ alpha,
               const float* __restrict__ f_rhs,
               float* __restrict__ out) {
    const int t    = threadIdx.x;
    const int lane = t & 63;
    const int w    = t >> 6;
    const int row  = blockIdx.x * WPB + w;
    const int s    = lane * CS;          // first global index of this chunk

    __shared__ float f_lds[1056];            // swizzled: h2*f[j] at sw(j)
    __shared__ float ostage[WPB][1056];      // swizzled per-wave output stage

    const float h2 = (float)(1.0 / (1023.0 * 1023.0));
    for (int i = t; i < NU; i += WPB * 64) f_lds[sw(i)] = h2 * f_rhs[i];
    if (t == 0) f_lds[sw(1023)] = 0.0f;      // identity-pad row: f = 0

    // ---------------- load K = exp(alpha) for this chunk (17 values) --------
    const float* arow = alpha + (size_t)row * MPTS;
    float kf[CS + 1];
    #pragma unroll
    for (int q = 0; q < 4; ++q) {
        const float4 v = *reinterpret_cast<const float4*>(arow + s + 4 * q);
        kf[4 * q + 0] = expf(v.x);
        kf[4 * q + 1] = expf(v.y);
        kf[4 * q + 2] = expf(v.z);
        kf[4 * q + 3] = expf(v.w);
    }
    {
        float kx = (lane < 63) ? arow[s + CS] : 0.0f;  // lane63: exp(0)=1
        kf[CS] = expf(kx);
    }
    // lane 63 pre-patch: kn at j=1022 -> 0 gives b=kc, d=0 there; at j=1023
    // kc=0, kn=1 gives the identity row (b=1) with f=0.
    if (lane == 63) kf[15] = 0.0f;

    __syncthreads();  // f_lds ready

    // ---------------- phase 1: boundary coefficients, zero arrays -----------
    // Forward chain:  u_i = uF_i + vF_i*uL - cF_i*u_{i+1}; at i=15:
    //   (De,Ae,Be) = (uF, vF, -cF).
    // Reverse chain:  u_i = uR_i + vR_i*uR + wR_i*u_{i-1}; at i=0:
    //   (Ds,Bs,As) = (uRv, vRv, wRv).
    float cF = (lane == 0) ? 1.0f : 0.0f, uF = 0.0f, vF = 1.0f;
    float uRv = 0.0f, vRv = 1.0f, wRv = 0.0f;
    #pragma unroll
    for (int i = 0; i < CS; ++i) {
        // forward step at index i
        {
            const float kc = kf[i], kn = kf[i + 1];
            const float b  = kc + kn;
            const float f  = f_lds[sw(s + i)];
            const float den = fmaf(kc, cF, b);
            const float r   = frcp(den);
            float ci = -kn * r;
            const float ui = fmaf(kc, uF, f) * r;
            const float vi = (kc * vF) * r;
            if (i == CS - 1) ci = (lane == 63) ? 0.0f : ci;  // pad row
            cF = ci; uF = ui; vF = vi;
        }
        // reverse step at index ir = 15-i
        {
            const int ir = CS - 1 - i;
            float kc = kf[ir];
            const float kn = kf[ir + 1];
            float b = kc + kn;
            if (ir == 0) {                     // j=0 boundary: b=2K0+K1, a=0
                b  = (lane == 0) ? (b + kc) : b;
                kc = (lane == 0) ? 0.0f : kc;
            }
            const float f  = f_lds[sw(s + ir)];
            const float den = fmaf(-kn, wRv, b);
            const float r   = frcp(den);
            const float ui = fmaf(kn, uRv, f) * r;
            const float vi = (kn * vRv) * r;
            const float wi = kc * r;
            uRv = ui; vRv = vi; wRv = wi;
        }
    }
    const float De_f = uF,  Ae_f = vF,  Be_f = -cF;
    const float Ds_f = uRv, Bs_f = vRv, As_f = wRv;

    // ---------------- phase 2: reduced boundary system (f64) ----------------
    // y_p = Ds + As*x_{p-1} + Bs*y_{p+1};  x_p = De + Ae*x_{p-1} + Be*y_{p+1}
    // Projective 3x3 suffix scan, kept normalized so m22 == 1 (6 entries).
    const double Ds = (double)Ds_f, As = (double)As_f, Bs = (double)Bs_f;
    const double De = (double)De_f, Ae = (double)Ae_f, Be = (double)Be_f;
    double m00 = Bs;
    double m01 = fma(Bs, De, -(Ds * Be));
    double m02 = Ds;
    double m11 = fma(Bs, Ae, -(As * Be));
    double m12 = As;
    double m21 = -Be;

    #pragma unroll
    for (int dlt = 1; dlt < 64; dlt <<= 1) {
        const bool val = (lane + dlt) < 64;
        double b00 = __shfl_down(m00, dlt); b00 = val ? b00 : 1.0;
        double b01 = __shfl_down(m01, dlt); b01 = val ? b01 : 0.0;
        double b02 = __shfl_down(m02, dlt); b02 = val ? b02 : 0.0;
        double b11 = __shfl_down(m11, dlt); b11 = val ? b11 : 1.0;
        double b12 = __shfl_down(m12, dlt); b12 = val ? b12 : 0.0;
        double b21 = __shfl_down(m21, dlt); b21 = val ? b21 : 0.0;
        const double n00 = m00 * b00;
        const double n01 = fma(m00, b01, fma(m01, b11, m02 * b21));
        const double n02 = fma(m00, b02, fma(m01, b12, m02));   // b22 == 1
        const double n11 = fma(m11, b11, m12 * b21);
        const double n12 = fma(m11, b12, m12);
        const double n21 = fma(m21, b11, b21);                  // m22 == 1
        const double n22 = fma(m21, b12, 1.0);
        const double rn = drcp(n22);       // n22 in (0,1]: strict dominance
        m00 = n00 * rn; m01 = n01 * rn; m02 = n02 * rn;
        m11 = n11 * rn; m12 = n12 * rn; m21 = n21 * rn;
    }
    // y_p = alf + bet * x_{p-1}   (m22 == 1)
    const double alf = m02;
    const double bet = m12;
    double alfn = __shfl_down(alf, 1); alfn = (lane == 63) ? 0.0 : alfn;
    double betn = __shfl_down(bet, 1); betn = (lane == 63) ? 0.0 : betn;

    // x_p = dl + gm * x_{p-1}
    const double tt = drcp(fma(-Be, betn, 1.0));
    const double dl = fma(Be, alfn, De) * tt;
    const double gm = Ae * tt;

    // Affine prefix scan for x (x_{-1} = 0).
    double X = dl, G = gm;
    #pragma unroll
    for (int dlt = 1; dlt < 64; dlt <<= 1) {
        double bx = __shfl_up(X, dlt);
        double bg = __shfl_up(G, dlt);
        const bool val = lane >= dlt;
        bx = val ? bx : 0.0;
        bg = val ? bg : 1.0;
        X = fma(G, bx, X);
        G = G * bg;
    }
    double xp = __shfl_up(X, 1);
    const double uLd = (lane == 0) ? 0.0 : xp;          // u_{s-1}
    const double Y   = fma(bet, uLd, alf);              // y_p = u_s
    double yn = __shfl_down(Y, 1);
    const double uRd = (lane == 63) ? 0.0 : yn;         // u_{e+1}

    // ---------------- phase 3: chunk re-solve with uL/uR folded into f ------
    const float uL = (float)uLd;
    const float uR = (float)uRd;
    float c3[CS], u3[CS];
    {
        float cp = (lane == 0) ? 1.0f : 0.0f, up = 0.0f;
        #pragma unroll
        for (int i = 0; i < CS; ++i) {
            const float kc = kf[i], kn = kf[i + 1];
            const float b  = kc + kn;
            float f = f_lds[sw(s + i)];
            if (i == 0)      f = fmaf(kf[0],  uL, f);   // lane0: uL==0
            if (i == CS - 1) f = fmaf(kf[CS], uR, f);   // lane63: uR==0
            const float den = fmaf(kc, cp, b);
            const float r   = frcp(den);
            const float ci = -kn * r;
            const float ui = fmaf(kc, up, f) * r;
            c3[i] = ci; u3[i] = ui;
            cp = ci; up = ui;
        }
    }
    // Back substitution: u_i = u3_i - c3_i * u_{i+1}; u_15 = u3_15 (uR folded).
    float* ost = ostage[w];
    {
        float un = u3[CS - 1];
        ost[sw(s + CS - 1)] = un;          // lane63 writes pad j=1023: harmless
        #pragma unroll
        for (int i = CS - 2; i >= 0; --i) {
            un = fmaf(-c3[i], un, u3[i]);
            ost[sw(s + i)] = un;
        }
    }
    __syncthreads();

    // Coalesced output: 64 lanes x 4B contiguous per instruction.
    float* orow = out + (size_t)row * NU;
    #pragma unroll
    for (int it = 0; it < 16; ++it) {
        const int c = it * 64 + lane;
        if (c < NU) orow[c] = ost[sw(c)];
    }
}

extern "C" void kernel_launch(void* const* d_in, const int* in_sizes, int n_in,
                              void* d_out, int out_size, void* d_ws, size_t ws_size,
                              hipStream_t stream) {
    const float* alpha = (const float*)d_in[0];
    const float* f_rhs = (const float*)d_in[1];
    float* out = (float*)d_out;

    dim3 grid(BT / WPB), block(WPB * 64);
    pt_kernel<<<grid, block, 0, stream>>>(alpha, f_rhs, out);
}

// Round 11
// 38.770 us; speedup vs baseline: 1.2302x; 1.0248x over previous
//
#include <hip/hip_runtime.h>
#include <math.h>

// Batched tridiagonal solve A(exp(alpha)) u = f_rhs via chunked partition
// (SPIKE-style). Round 11: 2 rows/wave (CS=32 geometry) but ALL f32 chains
// split into 16-step halves (CS=16 error growth — r9's proven 3.66e-4):
//  - phase 1: four independent 16-step chains (fwd/rev x half1/half2);
//    half triplets composed into the chunk triplet in f64 (exact 2x2
//    junction elimination, diagonally-dominant denominator).
//  - phase 2: f64 projective scan over 32-lane groups, verbatim r9/r10
//    (f32 scan FAILED r7; f64 required for the global kappa~n^2 solve).
//  - phase 3: junction values (u_mid, u_last1) in f64, then two independent
//    16-step f32 re-solves with exact Dirichlet data, reusing phase-1
//    reciprocals (division-free).
//  - evidence: r9 CS=16 chains -> 3.66e-4 PASS; r10 CS=32 chains -> 6.1e-4
//    FAIL. Error scales with chain length; geometry kept, chains halved.

constexpr int BT   = 16384;
constexpr int MPTS = 1024;
constexpr int NU   = 1023;   // real unknowns
constexpr int CS   = 32;     // chunk size (per lane)
constexpr int HS   = 16;     // half-chunk
constexpr int NG   = 32;     // chunks per row == lanes per group
constexpr int WPB  = 4;      // waves per block (each wave = 2 rows)
constexpr int RPB  = WPB*2;  // rows per block

__device__ __forceinline__ float frcp(float x) {
    float r = __builtin_amdgcn_rcpf(x);        // v_rcp_f32
    r = fmaf(r, fmaf(-x, r, 1.0f), r);         // 1 NR -> ~0.5 ulp
    return r;
}
__device__ __forceinline__ double drcp(double x) {
    double r = __builtin_amdgcn_rcp(x);        // v_rcp_f64, ~2^-27
    r = fma(r, fma(-x, r, 1.0), r);            // 1 NR -> ~2^-54
    return r;
}
__device__ __forceinline__ int sw(int j) { return j + (j >> 5); }

__global__ __launch_bounds__(WPB * 64, 3)
void pt_kernel(const float* __restrict__ alpha,
               const float* __restrict__ f_rhs,
               float* __restrict__ out) {
    const int t    = threadIdx.x;
    const int lane = t & 63;
    const int w    = t >> 6;
    const int g    = lane & 31;          // chunk index within row
    const int h    = lane >> 5;          // 0 = row A, 1 = row B
    const int rowbase = blockIdx.x * RPB + w * 2;
    const int row  = rowbase + h;
    const int s    = g * CS;             // first global index of this chunk

    __shared__ float f_lds[1056];            // swizzled: h2*f[j] at sw(j)
    __shared__ float ostage[WPB][1056];      // per-wave output stage

    const float h2 = (float)(1.0 / (1023.0 * 1023.0));
    for (int i = t; i < NU; i += WPB * 64) f_lds[sw(i)] = h2 * f_rhs[i];
    if (t == 0) f_lds[sw(1023)] = 0.0f;      // identity-pad row: f = 0

    // ---------------- load K = exp(alpha) for this chunk (33 values) --------
    const float* arow = alpha + (size_t)row * MPTS;
    float kf[CS + 1];
    #pragma unroll
    for (int q = 0; q < 8; ++q) {
        const float4 v = *reinterpret_cast<const float4*>(arow + s + 4 * q);
        kf[4 * q + 0] = expf(v.x);
        kf[4 * q + 1] = expf(v.y);
        kf[4 * q + 2] = expf(v.z);
        kf[4 * q + 3] = expf(v.w);
    }
    {
        float kx = (g < NG - 1) ? arow[s + CS] : 0.0f;  // g31: exp(0)=1
        kf[CS] = expf(kx);
    }
    // g==31 pre-patch: kn at j=1022 -> 0 gives b=kc, d=0 there; row j=1023
    // becomes the identity pad row (kc=0, kn=1, b=1, f=0).
    if (g == NG - 1) kf[CS - 1] = 0.0f;

    __syncthreads();  // f_lds ready

    // ---------------- phase 1: four independent 16-step chains --------------
    // fwd half: u_i = uF + vF*uLh - cF*u_{i+1}; at half end -> (De,Ae,Be).
    // rev half: u_i = uRv + vRv*uRh + wRv*u_{i-1}; at half start -> (Ds,Bs,As).
    float rA[CS];
    float cF1 = (g == 0) ? 1.0f : 0.0f, uF1 = 0.0f, vF1 = 1.0f;
    float cF2 = 0.0f,                   uF2 = 0.0f, vF2 = 1.0f;
    float u1r = 0.0f, v1r = 1.0f, w1r = 0.0f;
    float u2r = 0.0f, v2r = 1.0f, w2r = 0.0f;
    #pragma unroll
    for (int i = 0; i < HS; ++i) {
        // fwd1 at i
        {
            const float kc = kf[i], kn = kf[i + 1];
            const float b  = kc + kn;
            const float f  = f_lds[sw(s + i)];
            const float den = fmaf(kc, cF1, b);
            const float r   = frcp(den);
            rA[i] = r;
            cF1 = -kn * r;
            uF1 = fmaf(kc, uF1, f) * r;
            vF1 = (kc * vF1) * r;
        }
        // fwd2 at i2 = 16+i
        {
            const int i2 = HS + i;
            const float kc = kf[i2], kn = kf[i2 + 1];
            const float b  = kc + kn;
            const float f  = f_lds[sw(s + i2)];
            const float den = fmaf(kc, cF2, b);
            const float r   = frcp(den);
            rA[i2] = r;
            float ci = -kn * r;
            if (i2 == CS - 1) ci = (g == NG - 1) ? 0.0f : ci;  // pad row
            uF2 = fmaf(kc, uF2, f) * r;
            vF2 = (kc * vF2) * r;
            cF2 = ci;
        }
        // rev1 at ir = 15-i
        {
            const int ir = HS - 1 - i;
            float kc = kf[ir];
            const float kn = kf[ir + 1];
            float b = kc + kn;
            if (ir == 0) {                     // j=0 boundary: b=2K0+K1, a=0
                b  = (g == 0) ? (b + kc) : b;
                kc = (g == 0) ? 0.0f : kc;
            }
            const float f  = f_lds[sw(s + ir)];
            const float den = fmaf(-kn, w1r, b);
            const float r   = frcp(den);
            u1r = fmaf(kn, u1r, f) * r;
            v1r = (kn * v1r) * r;
            w1r = kc * r;
        }
        // rev2 at ir2 = 31-i
        {
            const int ir = CS - 1 - i;
            const float kc = kf[ir];
            const float kn = kf[ir + 1];
            const float b  = kc + kn;
            const float f  = f_lds[sw(s + ir)];
            const float den = fmaf(-kn, w2r, b);
            const float r   = frcp(den);
            u2r = fmaf(kn, u2r, f) * r;
            v2r = (kn * v2r) * r;
            w2r = kc * r;
        }
    }

    // ---------------- compose half triplets -> chunk triplet (f64) ----------
    const double De1 = (double)uF1, Ae1 = (double)vF1, Be1 = -(double)cF1;
    const double De2 = (double)uF2, Ae2 = (double)vF2, Be2 = -(double)cF2;
    const double Ds1 = (double)u1r, Bs1 = (double)v1r, As1 = (double)w1r;
    const double Ds2 = (double)u2r, Bs2 = (double)v2r, As2 = (double)w2r;

    // u_mid = u_{s+16} = P0 + PL*uL + PR*uR (junction 2x2 elimination)
    const double q  = drcp(fma(-As2, Be1, 1.0));
    const double P0 = q * fma(As2, De1, Ds2);
    const double PL = q * (As2 * Ae1);
    const double PR = q * Bs2;
    // u_last1 = u_{s+15} = L0 + LL*uL + LR*uR
    const double L0 = fma(Be1, P0, De1);
    const double LL = fma(Be1, PL, Ae1);
    const double LR = Be1 * PR;
    // chunk triplets
    const double Ds = fma(Bs1, P0, Ds1);
    const double As = fma(Bs1, PL, As1);
    const double Bs = Bs1 * PR;
    const double De = fma(Ae2, L0, De2);
    const double Ae = Ae2 * LL;
    const double Be = fma(Ae2, LR, Be2);

    // ---------------- phase 2: reduced boundary system (f64, per group) -----
    // y_p = Ds + As*x_{p-1} + Bs*y_{p+1};  x_p = De + Ae*x_{p-1} + Be*y_{p+1}
    // Projective 3x3 suffix scan over the 32-lane group (m22 kept == 1).
    double m00 = Bs;
    double m01 = fma(Bs, De, -(Ds * Be));
    double m02 = Ds;
    double m11 = fma(Bs, Ae, -(As * Be));
    double m12 = As;
    double m21 = -Be;

    #pragma unroll
    for (int dlt = 1; dlt < NG; dlt <<= 1) {
        const bool val = (g + dlt) < NG;
        double b00 = __shfl_down(m00, dlt); b00 = val ? b00 : 1.0;
        double b01 = __shfl_down(m01, dlt); b01 = val ? b01 : 0.0;
        double b02 = __shfl_down(m02, dlt); b02 = val ? b02 : 0.0;
        double b11 = __shfl_down(m11, dlt); b11 = val ? b11 : 1.0;
        double b12 = __shfl_down(m12, dlt); b12 = val ? b12 : 0.0;
        double b21 = __shfl_down(m21, dlt); b21 = val ? b21 : 0.0;
        const double n00 = m00 * b00;
        const double n01 = fma(m00, b01, fma(m01, b11, m02 * b21));
        const double n02 = fma(m00, b02, fma(m01, b12, m02));   // b22 == 1
        const double n11 = fma(m11, b11, m12 * b21);
        const double n12 = fma(m11, b12, m12);
        const double n21 = fma(m21, b11, b21);                  // m22 == 1
        const double n22 = fma(m21, b12, 1.0);
        const double rn = drcp(n22);       // n22 in (0,1]: strict dominance
        m00 = n00 * rn; m01 = n01 * rn; m02 = n02 * rn;
        m11 = n11 * rn; m12 = n12 * rn; m21 = n21 * rn;
    }
    // y_p = alf + bet * x_{p-1}   (m22 == 1)
    const double alf = m02;
    const double bet = m12;
    double alfn = __shfl_down(alf, 1); alfn = (g == NG - 1) ? 0.0 : alfn;
    double betn = __shfl_down(bet, 1); betn = (g == NG - 1) ? 0.0 : betn;

    // x_p = dl + gm * x_{p-1}
    const double tt = drcp(fma(-Be, betn, 1.0));
    const double dl = fma(Be, alfn, De) * tt;
    const double gm = Ae * tt;

    // Affine prefix scan for x within the group (x_{-1} = 0).
    double X = dl, G = gm;
    #pragma unroll
    for (int dlt = 1; dlt < NG; dlt <<= 1) {
        double bx = __shfl_up(X, dlt);
        double bg = __shfl_up(G, dlt);
        const bool val = g >= dlt;
        bx = val ? bx : 0.0;
        bg = val ? bg : 1.0;
        X = fma(G, bx, X);
        G = G * bg;
    }
    double xp = __shfl_up(X, 1);
    const double uLd = (g == 0) ? 0.0 : xp;           // u_{s-1}
    const double Y   = fma(bet, uLd, alf);            // y_p = u_s
    double yn = __shfl_down(Y, 1);
    const double uRd = (g == NG - 1) ? 0.0 : yn;      // u_{s+CS}

    // ---------------- junction values (f64) then two f32 half re-solves -----
    const double uMd  = fma(PL, uLd, fma(PR, uRd, P0));   // u_{s+16}
    const double uL1d = fma(LL, uLd, fma(LR, uRd, L0));   // u_{s+15}
    const float uL  = (float)uLd;
    const float uM  = (float)uMd;
    const float uL1 = (float)uL1d;
    const float uR  = (float)uRd;

    float u3[CS];
    {
        float up1 = 0.0f, up2 = 0.0f;
        #pragma unroll
        for (int i = 0; i < HS; ++i) {
            // half1: Dirichlet data (uL, uM)
            {
                float f = f_lds[sw(s + i)];
                if (i == 0)      f = fmaf(kf[0],  uL, f);   // g0: uL==0
                if (i == HS - 1) f = fmaf(kf[HS], uM, f);
                up1 = fmaf(kf[i], up1, f) * rA[i];
                u3[i] = up1;
                rA[i] = kf[i + 1] * rA[i];                  // backsub coeff
            }
            // half2: Dirichlet data (uL1, uR)
            {
                const int i2 = HS + i;
                float f = f_lds[sw(s + i2)];
                if (i == 0)      f = fmaf(kf[HS], uL1, f);
                if (i == HS - 1) f = fmaf(kf[CS], uR, f);   // g31: uR==0
                up2 = fmaf(kf[i2], up2, f) * rA[i2];
                u3[i2] = up2;
                rA[i2] = kf[i2 + 1] * rA[i2];               // backsub coeff
            }
        }
    }
    // Back substitution, both halves independent (1 fma/step each).
    {
        float un = u3[HS - 1];
        #pragma unroll
        for (int i = HS - 2; i >= 0; --i) {
            un = fmaf(rA[i], un, u3[i]);
            u3[i] = un;
        }
    }
    {
        float un = u3[CS - 1];
        #pragma unroll
        for (int i = CS - 2; i >= HS; --i) {
            un = fmaf(rA[i], un, u3[i]);
            u3[i] = un;
        }
    }

    // ---------------- output: stage+drain row A, then row B -----------------
    float* ost = ostage[w];
    if (h == 0) {
        #pragma unroll
        for (int i = 0; i < CS; ++i) ost[sw(s + i)] = u3[i];
    }
    __syncthreads();
    {
        float* orow = out + (size_t)rowbase * NU;
        #pragma unroll
        for (int it = 0; it < 16; ++it) {
            const int c = it * 64 + lane;
            if (c < NU) orow[c] = ost[sw(c)];
        }
    }
    __syncthreads();
    if (h == 1) {
        #pragma unroll
        for (int i = 0; i < CS; ++i) ost[sw(s + i)] = u3[i];
    }
    __syncthreads();
    {
        float* orow = out + (size_t)(rowbase + 1) * NU;
        #pragma unroll
        for (int it = 0; it < 16; ++it) {
            const int c = it * 64 + lane;
            if (c < NU) orow[c] = ost[sw(c)];
        }
    }
}

extern "C" void kernel_launch(void* const* d_in, const int* in_sizes, int n_in,
                              void* d_out, int out_size, void* d_ws, size_t ws_size,
                              hipStream_t stream) {
    const float* alpha = (const float*)d_in[0];
    const float* f_rhs = (const float*)d_in[1];
    float* out = (float*)d_out;

    dim3 grid(BT / RPB), block(WPB * 64);
    pt_kernel<<<grid, block, 0, stream>>>(alpha, f_rhs, out);
}